// Round 1
// baseline (16147.603 us; speedup 1.0000x reference)
//
#include <hip/hip_runtime.h>
#include <stdint.h>

// LSTM encoder: B=64, S=512, V=32000, E=512, H=1024. Returns final (h, c) fp32.
//
// Round-1 design: fold input projection into the recurrence:
//   gates_t = [h_{t-1} | emb_t] @ [W_hh ; W_ih] + b   (M=64, N=4096, K=1536)
// Persistent kernel, 64 blocks x 256 threads (co-resident on 256 CUs ->
// manual global barrier is safe). Block k owns 16 h-cols = 64 gate-cols.
// bf16 MFMA 16x16x32, fp32 accumulate. c-state in registers (block-private).
// h double-buffered as bf16 in ws; emb row for t+1 prefetched each step.

#define Bsz 64
#define Ssz 512
#define Esz 512
#define Hsz 1024
#define G4  4096
#define Ksz 1536   // H + E
#define NBLK 64

typedef float f32x4 __attribute__((ext_vector_type(4)));
typedef short bf16x8 __attribute__((ext_vector_type(8)));

__device__ __forceinline__ unsigned short f2bf(float f) {
  union { float f; uint32_t u; } v; v.f = f;
  return (unsigned short)((v.u + 0x7FFFu + ((v.u >> 16) & 1u)) >> 16);  // RNE
}
__device__ __forceinline__ float fsig(float x) {
  return __builtin_amdgcn_rcpf(1.0f + __expf(-x));
}
__device__ __forceinline__ float ftanh(float x) {
  return 2.0f * fsig(2.0f * x) - 1.0f;
}

// W_t[j][k] = (k < H ? W_hh[k][j] : W_ih[k-H][j]) as bf16. 32x32 LDS transpose.
__global__ __launch_bounds__(1024) void wt_kernel(
    const float* __restrict__ Wih, const float* __restrict__ Whh,
    unsigned short* __restrict__ Wt)
{
  __shared__ float tile[32][33];
  const int j0 = blockIdx.x * 32;           // gate-col block (4096/32)
  const int k0 = blockIdx.y * 32;           // k block (1536/32)
  const int tx = threadIdx.x & 31, ty = threadIdx.x >> 5;
  const int k = k0 + ty, j = j0 + tx;
  tile[ty][tx] = (k < Hsz) ? Whh[(size_t)k * G4 + j]
                           : Wih[(size_t)(k - Hsz) * G4 + j];
  __syncthreads();
  Wt[(size_t)(j0 + ty) * Ksz + (k0 + tx)] = f2bf(tile[tx][ty]);
}

// A0[row][0:1024] = 0 (h_{-1}); A0[row][1024:1536] = emb(seq[row][0]); bar = 0.
__global__ __launch_bounds__(256) void init_kernel(
    const int* __restrict__ seq, const float* __restrict__ emb,
    unsigned short* __restrict__ A0, int* __restrict__ bar)
{
  const int blk = blockIdx.x, tid = threadIdx.x;
  uint2 z; z.x = 0u; z.y = 0u;
  ((uint2*)(A0 + (size_t)blk * Ksz))[tid] = z;          // 256*8B = 1024 bf16
  const int token = seq[blk * Ssz];
  float2 e = ((const float2*)(emb + (size_t)token * Esz))[tid];
  uint32_t pe = (uint32_t)f2bf(e.x) | ((uint32_t)f2bf(e.y) << 16);
  ((uint32_t*)(A0 + (size_t)blk * Ksz + Hsz))[tid] = pe;
  if (blk == 0 && tid < 32) bar[tid] = 0;
}

__global__ __launch_bounds__(256) void lstm_kernel(
    const int* __restrict__ seq, const float* __restrict__ emb,
    const float* __restrict__ bias, const unsigned short* __restrict__ Wt,
    unsigned short* __restrict__ A0, unsigned short* __restrict__ A1,
    int* __restrict__ bar, float* __restrict__ out)
{
  const int blk  = blockIdx.x;          // 0..63, owns h-cols [blk*16, blk*16+16)
  const int tid  = threadIdx.x;
  const int lane = tid & 63;
  const int wave = tid >> 6;            // 4 waves, 2x2 tile grid
  const int mw = wave & 1, nw = wave >> 1;
  const int c0 = blk * 16;
  const int l15 = lane & 15, quad = lane >> 4;

  __shared__ float Gs[64][65];          // gate pre-activations (padded)

  // B-fragment row pointers. Block col n in [0,64): gate = n>>4, hcol = c0+(n&15)
  // -> W_t row = gate*1024 + c0 + (n&15). Wave nw covers n in [nw*32, nw*32+32).
  const unsigned short* bq0 = Wt + (size_t)((nw*2    ) * Hsz + c0 + l15) * Ksz + quad*8;
  const unsigned short* bq1 = Wt + (size_t)((nw*2 + 1) * Hsz + c0 + l15) * Ksz + quad*8;
  // A-fragment offsets: wave mw covers batch rows [mw*32, mw*32+32).
  const size_t aoff0 = (size_t)(mw*32      + l15) * Ksz + quad*8;
  const size_t aoff1 = (size_t)(mw*32 + 16 + l15) * Ksz + quad*8;

  // Elementwise ownership: thread -> (row = tid>>2, hcols ej0..ej0+3). Fixed
  // across steps so c lives in registers for the whole sequence.
  const int erow = tid >> 2;
  const int ej0  = (tid & 3) * 4;
  float creg[4] = {0.f, 0.f, 0.f, 0.f};
  float bi[4], bfg[4], bg[4], bo[4];
  #pragma unroll
  for (int q = 0; q < 4; ++q) {
    bi[q]  = bias[          c0 + ej0 + q];
    bfg[q] = bias[  Hsz   + c0 + ej0 + q];
    bg[q]  = bias[2*Hsz   + c0 + ej0 + q];
    bo[q]  = bias[3*Hsz   + c0 + ej0 + q];
  }

  int* cnt = bar;

  for (int t = 0; t < Ssz; ++t) {
    const unsigned short* Ac = (t & 1) ? A1 : A0;
    unsigned short*       An = (t & 1) ? A0 : A1;

    f32x4 acc00 = {0.f,0.f,0.f,0.f};
    f32x4 acc01 = acc00, acc10 = acc00, acc11 = acc00;
    const unsigned short* ap0 = Ac + aoff0;
    const unsigned short* ap1 = Ac + aoff1;
    const unsigned short* bp0 = bq0;
    const unsigned short* bp1 = bq1;
    #pragma unroll 4
    for (int kc = 0; kc < Ksz / 32; ++kc) {
      bf16x8 av0 = *(const bf16x8*)ap0;
      bf16x8 av1 = *(const bf16x8*)ap1;
      bf16x8 bv0 = *(const bf16x8*)bp0;
      bf16x8 bv1 = *(const bf16x8*)bp1;
      acc00 = __builtin_amdgcn_mfma_f32_16x16x32_bf16(av0, bv0, acc00, 0, 0, 0);
      acc01 = __builtin_amdgcn_mfma_f32_16x16x32_bf16(av0, bv1, acc01, 0, 0, 0);
      acc10 = __builtin_amdgcn_mfma_f32_16x16x32_bf16(av1, bv0, acc10, 0, 0, 0);
      acc11 = __builtin_amdgcn_mfma_f32_16x16x32_bf16(av1, bv1, acc11, 0, 0, 0);
      ap0 += 32; ap1 += 32; bp0 += 32; bp1 += 32;
    }
    {
      // C/D layout (m89-verified): col = lane&15, row = quad*4 + reg
      const int mr = mw*32 + quad*4;
      const int nc = nw*32 + l15;
      #pragma unroll
      for (int r = 0; r < 4; ++r) {
        Gs[mr + r     ][nc     ] = acc00[r];
        Gs[mr + r     ][nc + 16] = acc01[r];
        Gs[mr + 16 + r][nc     ] = acc10[r];
        Gs[mr + 16 + r][nc + 16] = acc11[r];
      }
    }
    __syncthreads();

    float hv[4];
    #pragma unroll
    for (int q = 0; q < 4; ++q) {
      const int j = ej0 + q;
      float gi = Gs[erow][     j] + bi[q];
      float gf = Gs[erow][16 + j] + bfg[q];
      float gg = Gs[erow][32 + j] + bg[q];
      float go = Gs[erow][48 + j] + bo[q];
      float c  = fsig(gf) * creg[q] + fsig(gi) * ftanh(gg);
      creg[q] = c;
      hv[q]   = fsig(go) * ftanh(c);
    }

    if (t < Ssz - 1) {
      // h_t (bf16) -> next A buffer, own 4 columns of own row
      uint2 hp;
      hp.x = (uint32_t)f2bf(hv[0]) | ((uint32_t)f2bf(hv[1]) << 16);
      hp.y = (uint32_t)f2bf(hv[2]) | ((uint32_t)f2bf(hv[3]) << 16);
      *(uint2*)(An + (size_t)erow * Ksz + c0 + ej0) = hp;
      // prefetch emb row for step t+1: block handles batch row == blk
      const int token = seq[blk * Ssz + t + 1];
      float2 e = ((const float2*)(emb + (size_t)token * Esz))[tid];
      uint32_t pe = (uint32_t)f2bf(e.x) | ((uint32_t)f2bf(e.y) << 16);
      ((uint32_t*)(An + (size_t)blk * Ksz + Hsz))[tid] = pe;

      // device-wide barrier (monotonic counter; blocks are co-resident)
      __builtin_amdgcn_fence(__ATOMIC_RELEASE, "agent");
      __syncthreads();
      if (tid == 0) {
        __hip_atomic_fetch_add(cnt, 1, __ATOMIC_RELAXED, __HIP_MEMORY_SCOPE_AGENT);
        while (__hip_atomic_load(cnt, __ATOMIC_RELAXED, __HIP_MEMORY_SCOPE_AGENT)
               < NBLK * (t + 1)) {
          __builtin_amdgcn_s_sleep(1);
        }
      }
      __syncthreads();
      __builtin_amdgcn_fence(__ATOMIC_ACQUIRE, "agent");
    } else {
      // final step: write h (full fp32, pre-rounding) and c to d_out
      #pragma unroll
      for (int q = 0; q < 4; ++q) {
        out[(size_t)erow * Hsz + c0 + ej0 + q] = hv[q];
        out[(size_t)(Bsz * Hsz) + (size_t)erow * Hsz + c0 + ej0 + q] = creg[q];
      }
    }
  }
}

extern "C" void kernel_launch(void* const* d_in, const int* in_sizes, int n_in,
                              void* d_out, int out_size, void* d_ws, size_t ws_size,
                              hipStream_t stream) {
  (void)in_sizes; (void)n_in; (void)out_size; (void)ws_size;
  const int*   seq  = (const int*)d_in[0];     // [64][512] int32
  const float* emb  = (const float*)d_in[1];   // [32000][512] fp32
  const float* Wih  = (const float*)d_in[2];   // [512][4096] fp32
  const float* Whh  = (const float*)d_in[3];   // [1024][4096] fp32
  const float* bias = (const float*)d_in[4];   // [4096] fp32
  float* out = (float*)d_out;                  // h[64][1024] then c[64][1024]

  unsigned short* Wt = (unsigned short*)d_ws;            // 4096*1536 bf16
  unsigned short* A0 = Wt + (size_t)G4 * Ksz;            // 64*1536 bf16
  unsigned short* A1 = A0 + (size_t)Bsz * Ksz;           // 64*1536 bf16
  int* bar = (int*)(A1 + (size_t)Bsz * Ksz);             // 16B-aligned here

  wt_kernel<<<dim3(128, 48), 1024, 0, stream>>>(Wih, Whh, Wt);
  init_kernel<<<NBLK, 256, 0, stream>>>(seq, emb, A0, bar);
  lstm_kernel<<<NBLK, 256, 0, stream>>>(seq, emb, bias, Wt, A0, A1, bar, out);
}

// Round 2
// 14796.156 us; speedup vs baseline: 1.0913x; 1.0913x over previous
//
#include <hip/hip_runtime.h>
#include <stdint.h>

// LSTM encoder: B=64, S=512, V=32000, E=512, H=1024. Returns final (h, c) fp32.
//
// Round-2: persistent kernel, 128 blocks x 256 threads. Block owns 8 h-cols
// (32 gate-cols). W_t slice (32 rows x 1536 bf16, +8 pad) staged in LDS ONCE
// -> immune to the per-step agent-fence L2 invalidate that made round 1
// latency-bound. Only the A=[h|emb] matrix (192KB) traverses the fence per
// step; per-XCD it refills L2 once. emb row for t+1 prefetched at step top.

#define Bsz 64
#define Ssz 512
#define Esz 512
#define Hsz 1024
#define G4  4096
#define Ksz 1536   // H + E
#define NBLK 128
#define COLS 8     // h-cols per block
#define WROWS 32   // 4*COLS gate-cols per block
#define WPAD 1544  // 1536 + 8 bf16 pad (breaks 3072B stride -> 2-way only)

typedef float f32x4 __attribute__((ext_vector_type(4)));
typedef short bf16x8 __attribute__((ext_vector_type(8)));

__device__ __forceinline__ unsigned short f2bf(float f) {
  union { float f; uint32_t u; } v; v.f = f;
  return (unsigned short)((v.u + 0x7FFFu + ((v.u >> 16) & 1u)) >> 16);  // RNE
}
__device__ __forceinline__ float fsig(float x) {
  return __builtin_amdgcn_rcpf(1.0f + __expf(-x));
}
__device__ __forceinline__ float ftanh(float x) {
  return 2.0f * fsig(2.0f * x) - 1.0f;
}

// W_t[j][k] = (k < H ? W_hh[k][j] : W_ih[k-H][j]) as bf16. 32x32 LDS transpose.
__global__ __launch_bounds__(1024) void wt_kernel(
    const float* __restrict__ Wih, const float* __restrict__ Whh,
    unsigned short* __restrict__ Wt)
{
  __shared__ float tile[32][33];
  const int j0 = blockIdx.x * 32;           // gate-col block (4096/32)
  const int k0 = blockIdx.y * 32;           // k block (1536/32)
  const int tx = threadIdx.x & 31, ty = threadIdx.x >> 5;
  const int k = k0 + ty, j = j0 + tx;
  tile[ty][tx] = (k < Hsz) ? Whh[(size_t)k * G4 + j]
                           : Wih[(size_t)(k - Hsz) * G4 + j];
  __syncthreads();
  Wt[(size_t)(j0 + ty) * Ksz + (k0 + tx)] = f2bf(tile[tx][ty]);
}

// A0[row][0:1024] = 0 (h_{-1}); A0[row][1024:1536] = emb(seq[row][0]); bar = 0.
__global__ __launch_bounds__(256) void init_kernel(
    const int* __restrict__ seq, const float* __restrict__ emb,
    unsigned short* __restrict__ A0, int* __restrict__ bar)
{
  const int blk = blockIdx.x, tid = threadIdx.x;
  uint2 z; z.x = 0u; z.y = 0u;
  ((uint2*)(A0 + (size_t)blk * Ksz))[tid] = z;          // 256*8B = 1024 bf16
  const int token = seq[blk * Ssz];
  float2 e = ((const float2*)(emb + (size_t)token * Esz))[tid];
  uint32_t pe = (uint32_t)f2bf(e.x) | ((uint32_t)f2bf(e.y) << 16);
  ((uint32_t*)(A0 + (size_t)blk * Ksz + Hsz))[tid] = pe;
  if (blk == 0 && tid < 32) bar[tid] = 0;
}

__global__ __launch_bounds__(256, 1) void lstm_kernel(
    const int* __restrict__ seq, const float* __restrict__ emb,
    const float* __restrict__ bias, const unsigned short* __restrict__ Wt,
    unsigned short* __restrict__ A0, unsigned short* __restrict__ A1,
    int* __restrict__ bar, float* __restrict__ out)
{
  const int blk  = blockIdx.x;          // 0..127, owns h-cols [blk*8, blk*8+8)
  const int tid  = threadIdx.x;
  const int lane = tid & 63;
  const int wave = tid >> 6;            // 4 waves: 2x2 over (M=64, N=32)
  const int mw = wave & 1, nw = wave >> 1;
  const int c0 = blk * COLS;
  const int l15 = lane & 15, quad = lane >> 4;

  __shared__ unsigned short Wl[WROWS][WPAD];   // ~99 KB
  __shared__ float Gs[64][33];                 // ~8.5 KB
  __shared__ int seqrow[Ssz];                  // 2 KB (blocks < 64 only)

  // ---- one-time staging: W slice -> LDS. local row r = g*8 + j maps to
  // W_t row g*1024 + c0 + j.
  for (int i = tid; i < WROWS * (Ksz / 8); i += 256) {
    const int r  = i / (Ksz / 8);
    const int kc = (i % (Ksz / 8)) * 8;
    const int grow = (r >> 3) * Hsz + c0 + (r & 7);
    *(bf16x8*)&Wl[r][kc] = *(const bf16x8*)(Wt + (size_t)grow * Ksz + kc);
  }
  if (blk < Bsz) {
    for (int i = tid; i < Ssz; i += 256) seqrow[i] = seq[blk * Ssz + i];
  }

  // elementwise ownership: thread -> (row = tid>>2, 2 h-cols ej, ej+1)
  const int erow = tid >> 2;
  const int ej   = (tid & 3) * 2;
  float creg[2] = {0.f, 0.f};
  float bi[2], bfg[2], bg[2], bo[2];
  #pragma unroll
  for (int q = 0; q < 2; ++q) {
    bi[q]  = bias[          c0 + ej + q];
    bfg[q] = bias[  Hsz   + c0 + ej + q];
    bg[q]  = bias[2*Hsz   + c0 + ej + q];
    bo[q]  = bias[3*Hsz   + c0 + ej + q];
  }
  __syncthreads();

  // MFMA fragment addresses
  const size_t aoff0 = (size_t)(mw * 32      + l15) * Ksz + quad * 8;
  const size_t aoff1 = (size_t)(mw * 32 + 16 + l15) * Ksz + quad * 8;
  const unsigned short* wl = &Wl[nw * 16 + l15][quad * 8];

  int* cnt = bar;

  for (int t = 0; t < Ssz; ++t) {
    const unsigned short* Ac = (t & 1) ? A1 : A0;
    unsigned short*       An = (t & 1) ? A0 : A1;

    // ---- prefetch emb row for t+1 (independent of step t data) ----
    if (t < Ssz - 1 && blk < Bsz) {
      const int token = seqrow[t + 1];
      float2 e = ((const float2*)(emb + (size_t)token * Esz))[tid];
      uint32_t pe = (uint32_t)f2bf(e.x) | ((uint32_t)f2bf(e.y) << 16);
      ((uint32_t*)(An + (size_t)blk * Ksz + Hsz))[tid] = pe;
    }

    // ---- gates GEMM: [64 x 1536] x [1536 x 32] ----
    f32x4 acc0 = {0.f, 0.f, 0.f, 0.f};
    f32x4 acc1 = acc0;
    const unsigned short* ap0 = Ac + aoff0;
    const unsigned short* ap1 = Ac + aoff1;
    #pragma unroll 6
    for (int kc = 0; kc < Ksz / 32; ++kc) {
      bf16x8 av0 = *(const bf16x8*)(ap0 + kc * 32);
      bf16x8 av1 = *(const bf16x8*)(ap1 + kc * 32);
      bf16x8 bv  = *(const bf16x8*)(wl + kc * 32);
      acc0 = __builtin_amdgcn_mfma_f32_16x16x32_bf16(av0, bv, acc0, 0, 0, 0);
      acc1 = __builtin_amdgcn_mfma_f32_16x16x32_bf16(av1, bv, acc1, 0, 0, 0);
    }
    {
      // C/D layout: col = lane&15, row = quad*4 + reg
      const int mr = mw * 32 + quad * 4;
      const int nc = nw * 16 + l15;
      #pragma unroll
      for (int r = 0; r < 4; ++r) {
        Gs[mr + r     ][nc] = acc0[r];
        Gs[mr + 16 + r][nc] = acc1[r];
      }
    }
    __syncthreads();

    // ---- elementwise LSTM cell (Gs col n = gate*8 + local h-col) ----
    float hv[2];
    #pragma unroll
    for (int q = 0; q < 2; ++q) {
      const int j = ej + q;
      float gi = Gs[erow][     j] + bi[q];
      float gf = Gs[erow][ 8 + j] + bfg[q];
      float gg = Gs[erow][16 + j] + bg[q];
      float go = Gs[erow][24 + j] + bo[q];
      float c  = fsig(gf) * creg[q] + fsig(gi) * ftanh(gg);
      creg[q] = c;
      hv[q]   = fsig(go) * ftanh(c);
    }

    if (t < Ssz - 1) {
      // h_t -> next A buffer (2 bf16 = 4B per thread)
      uint32_t hp = (uint32_t)f2bf(hv[0]) | ((uint32_t)f2bf(hv[1]) << 16);
      *(uint32_t*)(An + (size_t)erow * Ksz + c0 + ej) = hp;

      // device-wide barrier (monotonic counter; 128 blocks co-resident)
      __builtin_amdgcn_fence(__ATOMIC_RELEASE, "agent");
      __syncthreads();
      if (tid == 0) {
        __hip_atomic_fetch_add(cnt, 1, __ATOMIC_RELAXED, __HIP_MEMORY_SCOPE_AGENT);
        while (__hip_atomic_load(cnt, __ATOMIC_RELAXED, __HIP_MEMORY_SCOPE_AGENT)
               < NBLK * (t + 1)) {
          __builtin_amdgcn_s_sleep(1);
        }
      }
      __syncthreads();
      __builtin_amdgcn_fence(__ATOMIC_ACQUIRE, "agent");
    } else {
      // final step: write h then c (fp32, pre-rounding) to d_out
      #pragma unroll
      for (int q = 0; q < 2; ++q) {
        out[(size_t)erow * Hsz + c0 + ej + q] = hv[q];
        out[(size_t)(Bsz * Hsz) + (size_t)erow * Hsz + c0 + ej + q] = creg[q];
      }
    }
  }
}

extern "C" void kernel_launch(void* const* d_in, const int* in_sizes, int n_in,
                              void* d_out, int out_size, void* d_ws, size_t ws_size,
                              hipStream_t stream) {
  (void)in_sizes; (void)n_in; (void)out_size; (void)ws_size;
  const int*   seq  = (const int*)d_in[0];     // [64][512] int32
  const float* emb  = (const float*)d_in[1];   // [32000][512] fp32
  const float* Wih  = (const float*)d_in[2];   // [512][4096] fp32
  const float* Whh  = (const float*)d_in[3];   // [1024][4096] fp32
  const float* bias = (const float*)d_in[4];   // [4096] fp32
  float* out = (float*)d_out;                  // h[64][1024] then c[64][1024]

  unsigned short* Wt = (unsigned short*)d_ws;            // 4096*1536 bf16
  unsigned short* A0 = Wt + (size_t)G4 * Ksz;            // 64*1536 bf16
  unsigned short* A1 = A0 + (size_t)Bsz * Ksz;           // 64*1536 bf16
  int* bar = (int*)(A1 + (size_t)Bsz * Ksz);

  wt_kernel<<<dim3(128, 48), 1024, 0, stream>>>(Wih, Whh, Wt);
  init_kernel<<<Bsz, 256, 0, stream>>>(seq, emb, A0, bar);
  lstm_kernel<<<NBLK, 256, 0, stream>>>(seq, emb, bias, Wt, A0, A1, bar, out);
}

// Round 3
// 13215.936 us; speedup vs baseline: 1.2218x; 1.1196x over previous
//
#include <hip/hip_runtime.h>
#include <stdint.h>

// LSTM encoder: B=64, S=512, V=32000, E=512, H=1024. Returns final (h, c) fp32.
//
// Round-3: kill the per-step agent fences (they lower to buffer_wbl2 +
// buffer_inv = full L2 writeback/invalidate on every XCD every step — the
// fixed ~25us/step cost rounds 1-2 both hit). All cross-block data now moves
// via device-scope (sc1) relaxed atomics, served at the MALL coherence point:
//   - h / emb-prefetch stores into A buffers: __hip_atomic_store AGENT
//   - A-matrix loads in the K-loop:           __hip_atomic_load  AGENT (8B)
// Each wave drains its own sc1 stores (s_waitcnt 0) before the barrier
// arrival; the barrier counter is a RELAXED agent fetch_add + poll. No cache
// maintenance instructions anywhere in the loop. W slice stays in LDS; emb
// table reads stay normally cached (read-only).

#define Bsz 64
#define Ssz 512
#define Esz 512
#define Hsz 1024
#define G4  4096
#define Ksz 1536   // H + E
#define NBLK 128
#define COLS 8     // h-cols per block
#define WROWS 32   // 4*COLS gate-cols per block
#define WPAD 1560  // 1536 + 24 bf16 pad

typedef float f32x4 __attribute__((ext_vector_type(4)));
typedef short bf16x8 __attribute__((ext_vector_type(8)));
typedef unsigned long long u64;
typedef u64 u64x2 __attribute__((ext_vector_type(2)));

__device__ __forceinline__ unsigned short f2bf(float f) {
  union { float f; uint32_t u; } v; v.f = f;
  return (unsigned short)((v.u + 0x7FFFu + ((v.u >> 16) & 1u)) >> 16);  // RNE
}
__device__ __forceinline__ float fsig(float x) {
  return __builtin_amdgcn_rcpf(1.0f + __expf(-x));
}
__device__ __forceinline__ float ftanh(float x) {
  return 2.0f * fsig(2.0f * x) - 1.0f;
}

// W_t[j][k] = (k < H ? W_hh[k][j] : W_ih[k-H][j]) as bf16. 32x32 LDS transpose.
__global__ __launch_bounds__(1024) void wt_kernel(
    const float* __restrict__ Wih, const float* __restrict__ Whh,
    unsigned short* __restrict__ Wt)
{
  __shared__ float tile[32][33];
  const int j0 = blockIdx.x * 32;           // gate-col block (4096/32)
  const int k0 = blockIdx.y * 32;           // k block (1536/32)
  const int tx = threadIdx.x & 31, ty = threadIdx.x >> 5;
  const int k = k0 + ty, j = j0 + tx;
  tile[ty][tx] = (k < Hsz) ? Whh[(size_t)k * G4 + j]
                           : Wih[(size_t)(k - Hsz) * G4 + j];
  __syncthreads();
  Wt[(size_t)(j0 + ty) * Ksz + (k0 + tx)] = f2bf(tile[tx][ty]);
}

// A0[row][0:1024] = 0 (h_{-1}); A0[row][1024:1536] = emb(seq[row][0]); bar = 0.
__global__ __launch_bounds__(256) void init_kernel(
    const int* __restrict__ seq, const float* __restrict__ emb,
    unsigned short* __restrict__ A0, int* __restrict__ bar)
{
  const int blk = blockIdx.x, tid = threadIdx.x;
  uint2 z; z.x = 0u; z.y = 0u;
  ((uint2*)(A0 + (size_t)blk * Ksz))[tid] = z;          // 256*8B = 1024 bf16
  const int token = seq[blk * Ssz];
  float2 e = ((const float2*)(emb + (size_t)token * Esz))[tid];
  uint32_t pe = (uint32_t)f2bf(e.x) | ((uint32_t)f2bf(e.y) << 16);
  ((uint32_t*)(A0 + (size_t)blk * Ksz + Hsz))[tid] = pe;
  if (blk == 0 && tid < 32) bar[tid] = 0;
}

__global__ __launch_bounds__(256, 1) void lstm_kernel(
    const int* __restrict__ seq, const float* __restrict__ emb,
    const float* __restrict__ bias, const unsigned short* __restrict__ Wt,
    unsigned short* __restrict__ A0, unsigned short* __restrict__ A1,
    int* __restrict__ bar, float* __restrict__ out)
{
  const int blk  = blockIdx.x;          // 0..127, owns h-cols [blk*8, blk*8+8)
  const int tid  = threadIdx.x;
  const int lane = tid & 63;
  const int wave = tid >> 6;            // 4 waves: 2x2 over (M=64, N=32)
  const int mw = wave & 1, nw = wave >> 1;
  const int c0 = blk * COLS;
  const int l15 = lane & 15, quad = lane >> 4;

  __shared__ unsigned short Wl[WROWS][WPAD];   // ~97.5 KB
  __shared__ float Gs[64][33];                 // ~8.5 KB
  __shared__ int seqrow[Ssz];                  // 2 KB (blocks < 64 only)

  // ---- one-time staging: W slice -> LDS. local row r = g*8 + j maps to
  // W_t row g*1024 + c0 + j.
  for (int i = tid; i < WROWS * (Ksz / 8); i += 256) {
    const int r  = i / (Ksz / 8);
    const int kc = (i % (Ksz / 8)) * 8;
    const int grow = (r >> 3) * Hsz + c0 + (r & 7);
    *(bf16x8*)&Wl[r][kc] = *(const bf16x8*)(Wt + (size_t)grow * Ksz + kc);
  }
  if (blk < Bsz) {
    for (int i = tid; i < Ssz; i += 256) seqrow[i] = seq[blk * Ssz + i];
  }

  // elementwise ownership: thread -> (row = tid>>2, 2 h-cols ej, ej+1)
  const int erow = tid >> 2;
  const int ej   = (tid & 3) * 2;
  float creg[2] = {0.f, 0.f};
  float bi[2], bfg[2], bg[2], bo[2];
  #pragma unroll
  for (int q = 0; q < 2; ++q) {
    bi[q]  = bias[          c0 + ej + q];
    bfg[q] = bias[  Hsz   + c0 + ej + q];
    bg[q]  = bias[2*Hsz   + c0 + ej + q];
    bo[q]  = bias[3*Hsz   + c0 + ej + q];
  }
  __syncthreads();

  // MFMA fragment addresses (u64 units: Ksz shorts = 384 u64; quad*8 shorts
  // = quad*2 u64; one 32-short K-chunk = 8 u64; a 16B fragment = 2 u64)
  const size_t aoff0 = (size_t)(mw * 32      + l15) * (Ksz / 4) + quad * 2;
  const size_t aoff1 = (size_t)(mw * 32 + 16 + l15) * (Ksz / 4) + quad * 2;
  const unsigned short* wl = &Wl[nw * 16 + l15][quad * 8];

  int* cnt = bar;

  for (int t = 0; t < Ssz; ++t) {
    const unsigned short* Ac = (t & 1) ? A1 : A0;
    unsigned short*       An = (t & 1) ? A0 : A1;

    // ---- prefetch emb row for t+1 (indep of step t; An buffer is dead) ----
    if (t < Ssz - 1 && blk < Bsz) {
      const int token = seqrow[t + 1];
      float2 e = ((const float2*)(emb + (size_t)token * Esz))[tid];
      uint32_t pe = (uint32_t)f2bf(e.x) | ((uint32_t)f2bf(e.y) << 16);
      __hip_atomic_store((uint32_t*)(An + (size_t)blk * Ksz + Hsz) + tid, pe,
                         __ATOMIC_RELAXED, __HIP_MEMORY_SCOPE_AGENT);
    }

    // ---- gates GEMM: [64 x 1536] x [1536 x 32], A via device-scope loads ----
    f32x4 acc0 = {0.f, 0.f, 0.f, 0.f};
    f32x4 acc1 = acc0;
    const u64* ap0 = (const u64*)Ac + aoff0;
    const u64* ap1 = (const u64*)Ac + aoff1;
    #pragma unroll 8
    for (int kc = 0; kc < Ksz / 32; ++kc) {
      u64 a0l = __hip_atomic_load(ap0 + kc * 8,     __ATOMIC_RELAXED, __HIP_MEMORY_SCOPE_AGENT);
      u64 a0h = __hip_atomic_load(ap0 + kc * 8 + 1, __ATOMIC_RELAXED, __HIP_MEMORY_SCOPE_AGENT);
      u64 a1l = __hip_atomic_load(ap1 + kc * 8,     __ATOMIC_RELAXED, __HIP_MEMORY_SCOPE_AGENT);
      u64 a1h = __hip_atomic_load(ap1 + kc * 8 + 1, __ATOMIC_RELAXED, __HIP_MEMORY_SCOPE_AGENT);
      bf16x8 bv = *(const bf16x8*)(wl + kc * 32);
      u64x2 p0; p0.x = a0l; p0.y = a0h;
      u64x2 p1; p1.x = a1l; p1.y = a1h;
      bf16x8 av0 = __builtin_bit_cast(bf16x8, p0);
      bf16x8 av1 = __builtin_bit_cast(bf16x8, p1);
      acc0 = __builtin_amdgcn_mfma_f32_16x16x32_bf16(av0, bv, acc0, 0, 0, 0);
      acc1 = __builtin_amdgcn_mfma_f32_16x16x32_bf16(av1, bv, acc1, 0, 0, 0);
    }
    {
      // C/D layout: col = lane&15, row = quad*4 + reg
      const int mr = mw * 32 + quad * 4;
      const int nc = nw * 16 + l15;
      #pragma unroll
      for (int r = 0; r < 4; ++r) {
        Gs[mr + r     ][nc] = acc0[r];
        Gs[mr + 16 + r][nc] = acc1[r];
      }
    }
    __syncthreads();

    // ---- elementwise LSTM cell (Gs col n = gate*8 + local h-col) ----
    float hv[2];
    #pragma unroll
    for (int q = 0; q < 2; ++q) {
      const int j = ej + q;
      float gi = Gs[erow][     j] + bi[q];
      float gf = Gs[erow][ 8 + j] + bfg[q];
      float gg = Gs[erow][16 + j] + bg[q];
      float go = Gs[erow][24 + j] + bo[q];
      float c  = fsig(gf) * creg[q] + fsig(gi) * ftanh(gg);
      creg[q] = c;
      hv[q]   = fsig(go) * ftanh(c);
    }

    if (t < Ssz - 1) {
      // h_t -> next A buffer (2 bf16 = 4B per thread), device scope
      uint32_t hp = (uint32_t)f2bf(hv[0]) | ((uint32_t)f2bf(hv[1]) << 16);
      __hip_atomic_store((uint32_t*)(An + (size_t)erow * Ksz + c0 + ej), hp,
                         __ATOMIC_RELAXED, __HIP_MEMORY_SCOPE_AGENT);

      // ---- barrier: per-wave drain of sc1 stores, then counter ----
      __atomic_signal_fence(__ATOMIC_SEQ_CST);
      __builtin_amdgcn_s_waitcnt(0);     // THIS wave's stores globally visible
      __syncthreads();                   // all waves drained
      if (tid == 0) {
        __hip_atomic_fetch_add(cnt, 1, __ATOMIC_RELAXED, __HIP_MEMORY_SCOPE_AGENT);
        while (__hip_atomic_load(cnt, __ATOMIC_RELAXED, __HIP_MEMORY_SCOPE_AGENT)
               < NBLK * (t + 1)) {
          __builtin_amdgcn_s_sleep(1);
        }
      }
      __syncthreads();
      __atomic_signal_fence(__ATOMIC_SEQ_CST);
    } else {
      // final step: write h then c (fp32, pre-rounding) to d_out
      #pragma unroll
      for (int q = 0; q < 2; ++q) {
        out[(size_t)erow * Hsz + c0 + ej + q] = hv[q];
        out[(size_t)(Bsz * Hsz) + (size_t)erow * Hsz + c0 + ej + q] = creg[q];
      }
    }
  }
}

extern "C" void kernel_launch(void* const* d_in, const int* in_sizes, int n_in,
                              void* d_out, int out_size, void* d_ws, size_t ws_size,
                              hipStream_t stream) {
  (void)in_sizes; (void)n_in; (void)out_size; (void)ws_size;
  const int*   seq  = (const int*)d_in[0];     // [64][512] int32
  const float* emb  = (const float*)d_in[1];   // [32000][512] fp32
  const float* Wih  = (const float*)d_in[2];   // [512][4096] fp32
  const float* Whh  = (const float*)d_in[3];   // [1024][4096] fp32
  const float* bias = (const float*)d_in[4];   // [4096] fp32
  float* out = (float*)d_out;                  // h[64][1024] then c[64][1024]

  unsigned short* Wt = (unsigned short*)d_ws;            // 4096*1536 bf16
  unsigned short* A0 = Wt + (size_t)G4 * Ksz;            // 64*1536 bf16
  unsigned short* A1 = A0 + (size_t)Bsz * Ksz;           // 64*1536 bf16
  int* bar = (int*)(A1 + (size_t)Bsz * Ksz);

  wt_kernel<<<dim3(128, 48), 1024, 0, stream>>>(Wih, Whh, Wt);
  init_kernel<<<Bsz, 256, 0, stream>>>(seq, emb, A0, bar);
  lstm_kernel<<<NBLK, 256, 0, stream>>>(seq, emb, bias, Wt, A0, A1, bar, out);
}

// Round 4
// 10180.863 us; speedup vs baseline: 1.5861x; 1.2981x over previous
//
#include <hip/hip_runtime.h>
#include <stdint.h>

// LSTM encoder: B=64, S=512, V=32000, E=512, H=1024. Returns final (h, c) fp32.
//
// Round-4: per-step cost in r1-r3 was invariant ~26us with all pipes idle ->
// latency/contention, not bandwidth. Changes:
//  (1) Fragment-swizzled W (per block,kc,ntile) -> W loads are coalesced 1KB
//      wave-loads from L2 (L2-resident, no fences ever). Fragment-swizzled A
//      buffers -> A loads are coalesced 16B/lane sc1 loads from MALL, zero
//      duplication (wave = one M-tile, all N).
//  (2) Two-phase K-loop per 24-kc half: issue 48 independent u64 sc1 loads,
//      sched_barrier, then MFMA -> forced memory-level parallelism.
//  (3) Flag-tree barrier: per-block arrival flags on distinct 64B lines
//      (plain sc1 stores, no RMW contention); block0's wave aggregates via
//      per-lane spin; single release flag read-polled by all.

#define Bsz 64
#define Ssz 512
#define Esz 512
#define Hsz 1024
#define G4  4096
#define Ksz 1536   // H + E
#define KC  48     // Ksz/32
#define NBLK 64
#define COLS 16    // h-cols per block -> 64 gate-cols, N-tiles = 4

typedef float f32x4 __attribute__((ext_vector_type(4)));
typedef short bf16x8 __attribute__((ext_vector_type(8)));
typedef unsigned long long u64;
typedef u64 u64x2 __attribute__((ext_vector_type(2)));

// A/W unit layout (16B units of 8 bf16):
//   unit(row,kc,q) = kc*256 + (row>>4)*64 + q*16 + (row&15)
// Wave w A-load at kc: unit = kc*256 + w*64 + lane  -> coalesced.
// Wf unit(blk,kc,nt,q,r) = (blk*48+kc)*256 + nt*64 + q*16 + r -> coalesced.

__device__ __forceinline__ unsigned short f2bf(float f) {
  union { float f; uint32_t u; } v; v.f = f;
  return (unsigned short)((v.u + 0x7FFFu + ((v.u >> 16) & 1u)) >> 16);  // RNE
}
__device__ __forceinline__ float fsig(float x) {
  return __builtin_amdgcn_rcpf(1.0f + __expf(-x));
}
__device__ __forceinline__ float ftanh(float x) {
  return 2.0f * fsig(2.0f * x) - 1.0f;
}

// Build Wf directly from fp32 W_ih/W_hh with a 32x32 LDS transpose.
// grid (4096/32, 1536/32), 1024 threads.
__global__ __launch_bounds__(1024) void wf_kernel(
    const float* __restrict__ Wih, const float* __restrict__ Whh,
    unsigned short* __restrict__ Wf)
{
  __shared__ float tile[32][33];
  const int j0 = blockIdx.x * 32;           // gate-col tile
  const int k0 = blockIdx.y * 32;           // k tile
  const int tx = threadIdx.x & 31, ty = threadIdx.x >> 5;
  const int k = k0 + ty;
  tile[ty][tx] = (k < Hsz) ? Whh[(size_t)k * G4 + (j0 + tx)]
                           : Wih[(size_t)(k - Hsz) * G4 + (j0 + tx)];
  __syncthreads();
  if (threadIdx.x < 128) {
    const int gl = threadIdx.x & 31;        // local gate col
    const int q8 = threadIdx.x >> 5;        // q (k-octet within kc)
    const int g  = j0 + gl;
    const int blk = (g >> 4) & 63;
    const int nt  = g >> 10;
    const int r   = g & 15;
    const int kc  = k0 >> 5;
    unsigned short pack[8];
    #pragma unroll
    for (int jj = 0; jj < 8; ++jj) pack[jj] = f2bf(tile[q8 * 8 + jj][gl]);
    const size_t unit = (size_t)((blk * KC + kc) * 256 + nt * 64 + q8 * 16 + r);
    *(bf16x8*)(Wf + unit * 8) = *(bf16x8*)pack;
  }
}

// A0 init (swizzled): h-region zeros, emb(seq[row][0]) bf16; bar zeroed.
__global__ __launch_bounds__(256) void init_kernel(
    const int* __restrict__ seq, const float* __restrict__ emb,
    unsigned short* __restrict__ A0, int* __restrict__ bar)
{
  const int row = blockIdx.x, tid = threadIdx.x;
  const int rb = row >> 4, r16 = row & 15;
  if (tid < 128) {                     // 32 kc x 4 q zero units
    const int kc = tid >> 2, q = tid & 3;
    const size_t unit = (size_t)(kc * 256 + rb * 64 + q * 16 + r16);
    uint4 z; z.x = z.y = z.z = z.w = 0u;
    *(uint4*)(A0 + unit * 8) = z;
  }
  const int token = seq[row * Ssz];
  const int c = 2 * tid;
  float2 e = ((const float2*)(emb + (size_t)token * Esz))[tid];
  uint32_t pe = (uint32_t)f2bf(e.x) | ((uint32_t)f2bf(e.y) << 16);
  const int kc = 32 + (c >> 5), q = (c >> 3) & 3, j = c & 7;
  const size_t unit = (size_t)(kc * 256 + rb * 64 + q * 16 + r16);
  *(uint32_t*)(A0 + unit * 8 + j) = pe;
  if (row == 0) for (int i = tid; i < 1056; i += 256) bar[i] = 0;
}

__global__ __launch_bounds__(256, 1) void lstm_kernel(
    const int* __restrict__ seq, const float* __restrict__ emb,
    const float* __restrict__ bias, const unsigned short* __restrict__ Wf,
    unsigned short* __restrict__ A0, unsigned short* __restrict__ A1,
    int* __restrict__ bar, float* __restrict__ out)
{
  const int blk  = blockIdx.x;          // owns h-cols [blk*16, blk*16+16)
  const int tid  = threadIdx.x;
  const int lane = tid & 63;
  const int w    = tid >> 6;            // wave = M-tile (rows w*16..w*16+16)
  const int c0   = blk * COLS;
  const int l15  = lane & 15, quad = lane >> 4;

  __shared__ float Gs[64][65];          // 64 rows x 64 gate-cols (+1 pad)
  __shared__ int seqrow[Ssz];

  for (int i = tid; i < Ssz; i += 256) seqrow[i] = seq[blk * Ssz + i];

  // elementwise ownership: thread -> (row = tid&63, 4 h-cols cg..cg+3)
  const int erow = tid & 63;
  const int cg   = (tid >> 6) * 4;
  const int erb  = erow >> 4, er16 = erow & 15;
  float creg[4] = {0.f, 0.f, 0.f, 0.f};
  float bi[4], bfg[4], bg_[4], bo[4];
  #pragma unroll
  for (int i = 0; i < 4; ++i) {
    bi[i]  = bias[          c0 + cg + i];
    bfg[i] = bias[  Hsz   + c0 + cg + i];
    bg_[i] = bias[2*Hsz   + c0 + cg + i];
    bo[i]  = bias[3*Hsz   + c0 + cg + i];
  }
  // h-store address pieces (cols c0+cg..+3: same kc, same q, j0..j0+3)
  const int hkc = (c0 + cg) >> 5, hq = ((c0 + cg) >> 3) & 3, hj0 = cg & 7;
  const size_t hunit = (size_t)(hkc * 256 + erb * 64 + hq * 16 + er16);

  const unsigned short* wfb = Wf + (size_t)blk * KC * 256 * 8;
  __syncthreads();

  for (int t = 0; t < Ssz; ++t) {
    const unsigned short* Ac = (t & 1) ? A1 : A0;
    unsigned short*       An = (t & 1) ? A0 : A1;

    // ---- prefetch emb row for t+1 into An (swizzled), device scope ----
    if (t < Ssz - 1) {
      const int token = seqrow[t + 1];
      const int c = 2 * tid;
      float2 e = ((const float2*)(emb + (size_t)token * Esz))[tid];
      uint32_t pe = (uint32_t)f2bf(e.x) | ((uint32_t)f2bf(e.y) << 16);
      const int kc = 32 + (c >> 5), q = (c >> 3) & 3, j = c & 7;
      const size_t unit = (size_t)(kc * 256 + (blk >> 4) * 64 + q * 16 + (blk & 15));
      __hip_atomic_store((uint32_t*)(An + unit * 8 + j), pe,
                         __ATOMIC_RELAXED, __HIP_MEMORY_SCOPE_AGENT);
    }

    // ---- gates GEMM: rows w*16..+16, all 64 N-cols, K=1536 ----
    f32x4 acc0 = {0.f,0.f,0.f,0.f};
    f32x4 acc1 = acc0, acc2 = acc0, acc3 = acc0;
    const u64* Ac64 = (const u64*)Ac;
    #pragma unroll
    for (int half = 0; half < 2; ++half) {
      u64 abuf[48];
      #pragma unroll
      for (int i = 0; i < 24; ++i) {
        const int kc = half * 24 + i;
        const size_t idx = (size_t)(kc * 256 + w * 64 + lane) * 2;
        abuf[2*i]   = __hip_atomic_load(Ac64 + idx,     __ATOMIC_RELAXED, __HIP_MEMORY_SCOPE_AGENT);
        abuf[2*i+1] = __hip_atomic_load(Ac64 + idx + 1, __ATOMIC_RELAXED, __HIP_MEMORY_SCOPE_AGENT);
      }
      __builtin_amdgcn_sched_barrier(0);   // keep all 48 loads clustered
      #pragma unroll
      for (int i = 0; i < 24; ++i) {
        const int kc = half * 24 + i;
        u64x2 p; p.x = abuf[2*i]; p.y = abuf[2*i+1];
        bf16x8 av = __builtin_bit_cast(bf16x8, p);
        const unsigned short* wp = wfb + (size_t)(kc * 256 + lane) * 8;
        bf16x8 bv0 = *(const bf16x8*)(wp);
        bf16x8 bv1 = *(const bf16x8*)(wp + 64 * 8);
        bf16x8 bv2 = *(const bf16x8*)(wp + 128 * 8);
        bf16x8 bv3 = *(const bf16x8*)(wp + 192 * 8);
        acc0 = __builtin_amdgcn_mfma_f32_16x16x32_bf16(av, bv0, acc0, 0, 0, 0);
        acc1 = __builtin_amdgcn_mfma_f32_16x16x32_bf16(av, bv1, acc1, 0, 0, 0);
        acc2 = __builtin_amdgcn_mfma_f32_16x16x32_bf16(av, bv2, acc2, 0, 0, 0);
        acc3 = __builtin_amdgcn_mfma_f32_16x16x32_bf16(av, bv3, acc3, 0, 0, 0);
      }
    }
    {
      // C/D layout: col = lane&15, row = quad*4 + reg
      const int mr = w * 16 + quad * 4;
      #pragma unroll
      for (int r = 0; r < 4; ++r) {
        Gs[mr + r][      l15] = acc0[r];
        Gs[mr + r][16 +  l15] = acc1[r];
        Gs[mr + r][32 +  l15] = acc2[r];
        Gs[mr + r][48 +  l15] = acc3[r];
      }
    }
    __syncthreads();

    // ---- elementwise LSTM cell ----
    float hv[4];
    #pragma unroll
    for (int i = 0; i < 4; ++i) {
      const int lc = cg + i;
      float gi = Gs[erow][     lc] + bi[i];
      float gf = Gs[erow][16 + lc] + bfg[i];
      float gg = Gs[erow][32 + lc] + bg_[i];
      float go = Gs[erow][48 + lc] + bo[i];
      float c  = fsig(gf) * creg[i] + fsig(gi) * ftanh(gg);
      creg[i] = c;
      hv[i]   = fsig(go) * ftanh(c);
    }

    if (t < Ssz - 1) {
      // h_t (4 bf16 = 8B) -> next A buffer, device scope
      uint32_t lo = (uint32_t)f2bf(hv[0]) | ((uint32_t)f2bf(hv[1]) << 16);
      uint32_t hi = (uint32_t)f2bf(hv[2]) | ((uint32_t)f2bf(hv[3]) << 16);
      u64 hp = (u64)lo | ((u64)hi << 32);
      __hip_atomic_store((u64*)(An + hunit * 8 + hj0), hp,
                         __ATOMIC_RELAXED, __HIP_MEMORY_SCOPE_AGENT);

      // ---- flag-tree barrier ----
      __builtin_amdgcn_s_waitcnt(0);     // this wave's sc1 stores at MALL
      __syncthreads();                   // all waves drained
      if (w == 0) {
        if (lane == 0)                   // arrival: own 64B line, no RMW
          __hip_atomic_store(&bar[16 + blk * 16], t + 1,
                             __ATOMIC_RELAXED, __HIP_MEMORY_SCOPE_AGENT);
        if (blk == 0) {
          // aggregator: lane i spins on block i's flag (per-lane AND)
          while (__hip_atomic_load(&bar[16 + lane * 16],
                                   __ATOMIC_RELAXED, __HIP_MEMORY_SCOPE_AGENT)
                 < t + 1) {
            __builtin_amdgcn_s_sleep(1);
          }
          if (lane == 0)
            __hip_atomic_store(&bar[0], t + 1,
                               __ATOMIC_RELAXED, __HIP_MEMORY_SCOPE_AGENT);
        }
        if (lane == 0) {                 // release poll (read-only line)
          while (__hip_atomic_load(&bar[0],
                                   __ATOMIC_RELAXED, __HIP_MEMORY_SCOPE_AGENT)
                 < t + 1) {
            __builtin_amdgcn_s_sleep(1);
          }
        }
      }
      __syncthreads();
    } else {
      // final step: write h then c (fp32) to d_out, 16B stores
      float4 ho; ho.x = hv[0]; ho.y = hv[1]; ho.z = hv[2]; ho.w = hv[3];
      float4 co; co.x = creg[0]; co.y = creg[1]; co.z = creg[2]; co.w = creg[3];
      *(float4*)&out[(size_t)erow * Hsz + c0 + cg] = ho;
      *(float4*)&out[(size_t)(Bsz * Hsz) + (size_t)erow * Hsz + c0 + cg] = co;
    }
  }
}

extern "C" void kernel_launch(void* const* d_in, const int* in_sizes, int n_in,
                              void* d_out, int out_size, void* d_ws, size_t ws_size,
                              hipStream_t stream) {
  (void)in_sizes; (void)n_in; (void)out_size; (void)ws_size;
  const int*   seq  = (const int*)d_in[0];     // [64][512] int32
  const float* emb  = (const float*)d_in[1];   // [32000][512] fp32
  const float* Wih  = (const float*)d_in[2];   // [512][4096] fp32
  const float* Whh  = (const float*)d_in[3];   // [1024][4096] fp32
  const float* bias = (const float*)d_in[4];   // [4096] fp32
  float* out = (float*)d_out;                  // h[64][1024] then c[64][1024]

  unsigned short* Wf = (unsigned short*)d_ws;            // 64*48*256*8 bf16 = 12.6MB
  unsigned short* A0 = Wf + (size_t)NBLK * KC * 256 * 8; // 12288 units = 192KB
  unsigned short* A1 = A0 + (size_t)12288 * 8;
  int* bar = (int*)(A1 + (size_t)12288 * 8);             // 1056 ints

  wf_kernel<<<dim3(G4 / 32, Ksz / 32), 1024, 0, stream>>>(Wih, Whh, Wf);
  init_kernel<<<Bsz, 256, 0, stream>>>(seq, emb, A0, bar);
  lstm_kernel<<<NBLK, 256, 0, stream>>>(seq, emb, bias, Wf, A0, A1, bar, out);
}

// Round 5
// 8314.975 us; speedup vs baseline: 1.9420x; 1.2244x over previous
//
#include <hip/hip_runtime.h>
#include <stdint.h>

// LSTM encoder: B=64, S=512, V=32000, E=512, H=1024. Returns final (h, c) fp32.
//
// Round-5: r1-r4 invariant ~20-30us/step with all pipes idle = request-rate
// bottleneck at the MALL: every block re-read the full A=[h|emb] (192KB x 64
// blocks = 12MB/step) as fine-grained UNCACHED device-scope reads. Fix: let
// per-XCD L2 broadcast A. Coherence without fences via VIRGIN BUFFER
// ROTATION: each timestep gets its own A buffer (512 x 192KB). Producers
// write h/emb with sc1 (write-through to MALL); consumers use NORMAL cached
// loads -- the lines are virgin this dispatch, so first touch cold-misses to
// MALL (fresh data) and subsequent blocks on the same XCD hit L2 (~200cy).
// MALL read traffic drops 8x (1.5MB/step), request count ~8x. Also: dropped
// the r4 abuf[48] staging (VGPR=256, likely spills) for plain pipelined
// loads, and flattened the barrier (every block's wave0 polls all 64 arrival
// flags directly; lane i polls flag i).

#define Bsz 64
#define Ssz 512
#define Esz 512
#define Hsz 1024
#define G4  4096
#define Ksz 1536   // H + E
#define KC  48     // Ksz/32
#define NBLK 64
#define COLS 16    // h-cols per block -> 64 gate-cols, N-tiles = 4
#define AUNITS 12288           // 16B units per A buffer (KC*256)
#define ABYTES (AUNITS * 16)   // 196608 B

typedef float f32x4 __attribute__((ext_vector_type(4)));
typedef short bf16x8 __attribute__((ext_vector_type(8)));
typedef unsigned long long u64;

// A/W unit layout (16B units of 8 bf16):
//   A unit(row,kc,q) = kc*256 + (row>>4)*64 + q*16 + (row&15)
//   wave w A-load at kc: unit = kc*256 + w*64 + lane  -> coalesced 1KB.
//   Wf unit(blk,kc,nt,q,r) = (blk*48+kc)*256 + nt*64 + q*16 + r -> coalesced.

__device__ __forceinline__ unsigned short f2bf(float f) {
  union { float f; uint32_t u; } v; v.f = f;
  return (unsigned short)((v.u + 0x7FFFu + ((v.u >> 16) & 1u)) >> 16);  // RNE
}
__device__ __forceinline__ float fsig(float x) {
  return __builtin_amdgcn_rcpf(1.0f + __expf(-x));
}
__device__ __forceinline__ float ftanh(float x) {
  return 2.0f * fsig(2.0f * x) - 1.0f;
}

// Build Wf from fp32 W_ih/W_hh with a 32x32 LDS transpose.
__global__ __launch_bounds__(1024) void wf_kernel(
    const float* __restrict__ Wih, const float* __restrict__ Whh,
    unsigned short* __restrict__ Wf)
{
  __shared__ float tile[32][33];
  const int j0 = blockIdx.x * 32;           // gate-col tile
  const int k0 = blockIdx.y * 32;           // k tile
  const int tx = threadIdx.x & 31, ty = threadIdx.x >> 5;
  const int k = k0 + ty;
  tile[ty][tx] = (k < Hsz) ? Whh[(size_t)k * G4 + (j0 + tx)]
                           : Wih[(size_t)(k - Hsz) * G4 + (j0 + tx)];
  __syncthreads();
  if (threadIdx.x < 128) {
    const int gl = threadIdx.x & 31;        // local gate col
    const int q8 = threadIdx.x >> 5;        // k-octet within kc
    const int g  = j0 + gl;
    const int blk = (g >> 4) & 63;
    const int nt  = g >> 10;
    const int r   = g & 15;
    const int kc  = k0 >> 5;
    unsigned short pack[8];
    #pragma unroll
    for (int jj = 0; jj < 8; ++jj) pack[jj] = f2bf(tile[q8 * 8 + jj][gl]);
    const size_t unit = (size_t)((blk * KC + kc) * 256 + nt * 64 + q8 * 16 + r);
    *(bf16x8*)(Wf + unit * 8) = *(bf16x8*)pack;
  }
}

// B[0] init (swizzled): h-region zeros, emb(seq[row][0]) bf16; flags zeroed.
__global__ __launch_bounds__(256) void init_kernel(
    const int* __restrict__ seq, const float* __restrict__ emb,
    unsigned short* __restrict__ A0, int* __restrict__ bar)
{
  const int row = blockIdx.x, tid = threadIdx.x;
  const int rb = row >> 4, r16 = row & 15;
  if (tid < 128) {                     // 32 kc x 4 q zero units
    const int kc = tid >> 2, q = tid & 3;
    const size_t unit = (size_t)(kc * 256 + rb * 64 + q * 16 + r16);
    uint4 z; z.x = z.y = z.z = z.w = 0u;
    *(uint4*)(A0 + unit * 8) = z;
  }
  const int token = seq[row * Ssz];
  const int c = 2 * tid;
  float2 e = ((const float2*)(emb + (size_t)token * Esz))[tid];
  uint32_t pe = (uint32_t)f2bf(e.x) | ((uint32_t)f2bf(e.y) << 16);
  const int kc = 32 + (c >> 5), q = (c >> 3) & 3, j = c & 7;
  const size_t unit = (size_t)(kc * 256 + rb * 64 + q * 16 + r16);
  *(uint32_t*)(A0 + unit * 8 + j) = pe;
  if (row == 0) for (int i = tid; i < 1056; i += 256) bar[i] = 0;
}

__global__ __launch_bounds__(256, 1) void lstm_kernel(
    const int* __restrict__ seq, const float* __restrict__ emb,
    const float* __restrict__ bias, const unsigned short* __restrict__ Wf,
    unsigned short* __restrict__ Abufs,
    int* __restrict__ bar, float* __restrict__ out)
{
  const int blk  = blockIdx.x;          // owns h-cols [blk*16, blk*16+16)
  const int tid  = threadIdx.x;
  const int lane = tid & 63;
  const int w    = tid >> 6;            // wave = M-tile (rows w*16..w*16+16)
  const int c0   = blk * COLS;
  const int l15  = lane & 15, quad = lane >> 4;

  __shared__ float Gs[64][65];          // 64 rows x 64 gate-cols (+1 pad)
  __shared__ int seqrow[Ssz];

  for (int i = tid; i < Ssz; i += 256) seqrow[i] = seq[blk * Ssz + i];

  // elementwise ownership: thread -> (row = tid&63, 4 h-cols cg..cg+3)
  const int erow = tid & 63;
  const int cg   = (tid >> 6) * 4;
  const int erb  = erow >> 4, er16 = erow & 15;
  float creg[4] = {0.f, 0.f, 0.f, 0.f};
  float bi[4], bfg[4], bg_[4], bo[4];
  #pragma unroll
  for (int i = 0; i < 4; ++i) {
    bi[i]  = bias[          c0 + cg + i];
    bfg[i] = bias[  Hsz   + c0 + cg + i];
    bg_[i] = bias[2*Hsz   + c0 + cg + i];
    bo[i]  = bias[3*Hsz   + c0 + cg + i];
  }
  // h-store address pieces (cols c0+cg..+3: same kc, same q, j0..j0+3)
  const int hkc = (c0 + cg) >> 5, hq = ((c0 + cg) >> 3) & 3, hj0 = cg & 7;
  const size_t hunit = (size_t)(hkc * 256 + erb * 64 + hq * 16 + er16);

  const uint4* wfb = (const uint4*)(Wf + (size_t)blk * KC * 256 * 8);
  __syncthreads();

  for (int t = 0; t < Ssz; ++t) {
    const uint4* Ac = (const uint4*)(Abufs + (size_t)t * AUNITS * 8);
    unsigned short* An = Abufs + (size_t)(t + 1) * AUNITS * 8;

    // ---- prefetch emb row for t+1 into B[t+1] (sc1, swizzled) ----
    if (t < Ssz - 1) {
      const int token = seqrow[t + 1];
      const int c = 2 * tid;
      float2 e = ((const float2*)(emb + (size_t)token * Esz))[tid];
      uint32_t pe = (uint32_t)f2bf(e.x) | ((uint32_t)f2bf(e.y) << 16);
      const int kc = 32 + (c >> 5), q = (c >> 3) & 3, j = c & 7;
      const size_t unit = (size_t)(kc * 256 + (blk >> 4) * 64 + q * 16 + (blk & 15));
      __hip_atomic_store((uint32_t*)(An + unit * 8 + j), pe,
                         __ATOMIC_RELAXED, __HIP_MEMORY_SCOPE_AGENT);
    }

    // ---- gates GEMM: rows w*16..+16, all 64 N-cols, K=1536 ----
    // A and W via NORMAL cached loads (virgin lines -> L2-shared broadcast)
    f32x4 acc0 = {0.f,0.f,0.f,0.f};
    f32x4 acc1 = acc0, acc2 = acc0, acc3 = acc0;
    #pragma unroll 8
    for (int kc = 0; kc < KC; ++kc) {
      uint4 a = Ac[kc * 256 + w * 64 + lane];
      const uint4* wp = wfb + kc * 256 + lane;
      uint4 b0 = wp[0];
      uint4 b1 = wp[64];
      uint4 b2 = wp[128];
      uint4 b3 = wp[192];
      bf16x8 av  = __builtin_bit_cast(bf16x8, a);
      bf16x8 bv0 = __builtin_bit_cast(bf16x8, b0);
      bf16x8 bv1 = __builtin_bit_cast(bf16x8, b1);
      bf16x8 bv2 = __builtin_bit_cast(bf16x8, b2);
      bf16x8 bv3 = __builtin_bit_cast(bf16x8, b3);
      acc0 = __builtin_amdgcn_mfma_f32_16x16x32_bf16(av, bv0, acc0, 0, 0, 0);
      acc1 = __builtin_amdgcn_mfma_f32_16x16x32_bf16(av, bv1, acc1, 0, 0, 0);
      acc2 = __builtin_amdgcn_mfma_f32_16x16x32_bf16(av, bv2, acc2, 0, 0, 0);
      acc3 = __builtin_amdgcn_mfma_f32_16x16x32_bf16(av, bv3, acc3, 0, 0, 0);
    }
    {
      // C/D layout: col = lane&15, row = quad*4 + reg
      const int mr = w * 16 + quad * 4;
      #pragma unroll
      for (int r = 0; r < 4; ++r) {
        Gs[mr + r][      l15] = acc0[r];
        Gs[mr + r][16 +  l15] = acc1[r];
        Gs[mr + r][32 +  l15] = acc2[r];
        Gs[mr + r][48 +  l15] = acc3[r];
      }
    }
    __syncthreads();

    // ---- elementwise LSTM cell ----
    float hv[4];
    #pragma unroll
    for (int i = 0; i < 4; ++i) {
      const int lc = cg + i;
      float gi = Gs[erow][     lc] + bi[i];
      float gf = Gs[erow][16 + lc] + bfg[i];
      float gg = Gs[erow][32 + lc] + bg_[i];
      float go = Gs[erow][48 + lc] + bo[i];
      float c  = fsig(gf) * creg[i] + fsig(gi) * ftanh(gg);
      creg[i] = c;
      hv[i]   = fsig(go) * ftanh(c);
    }

    if (t < Ssz - 1) {
      // h_t (4 bf16 = 8B) -> B[t+1], device scope (write-through to MALL)
      uint32_t lo = (uint32_t)f2bf(hv[0]) | ((uint32_t)f2bf(hv[1]) << 16);
      uint32_t hi = (uint32_t)f2bf(hv[2]) | ((uint32_t)f2bf(hv[3]) << 16);
      u64 hp = (u64)lo | ((u64)hi << 32);
      __hip_atomic_store((u64*)(An + hunit * 8 + hj0), hp,
                         __ATOMIC_RELAXED, __HIP_MEMORY_SCOPE_AGENT);

      // ---- flat flag barrier ----
      __builtin_amdgcn_s_waitcnt(0);     // this wave's sc1 stores at MALL
      __syncthreads();                   // all waves drained
      if (w == 0) {
        if (lane == 0)                   // arrival: own 64B line, plain store
          __hip_atomic_store(&bar[16 + blk * 16], t + 1,
                             __ATOMIC_RELAXED, __HIP_MEMORY_SCOPE_AGENT);
        // every block polls all 64 flags itself (lane i -> flag i);
        // exec-mask retires satisfied lanes, wave exits when all are done
        while (__hip_atomic_load(&bar[16 + lane * 16],
                                 __ATOMIC_RELAXED, __HIP_MEMORY_SCOPE_AGENT)
               < t + 1) {
          __builtin_amdgcn_s_sleep(2);
        }
      }
      __syncthreads();
    } else {
      // final step: write h then c (fp32) to d_out, 16B stores
      float4 ho; ho.x = hv[0]; ho.y = hv[1]; ho.z = hv[2]; ho.w = hv[3];
      float4 co; co.x = creg[0]; co.y = creg[1]; co.z = creg[2]; co.w = creg[3];
      *(float4*)&out[(size_t)erow * Hsz + c0 + cg] = ho;
      *(float4*)&out[(size_t)(Bsz * Hsz) + (size_t)erow * Hsz + c0 + cg] = co;
    }
  }
}

extern "C" void kernel_launch(void* const* d_in, const int* in_sizes, int n_in,
                              void* d_out, int out_size, void* d_ws, size_t ws_size,
                              hipStream_t stream) {
  (void)in_sizes; (void)n_in; (void)out_size; (void)ws_size;
  const int*   seq  = (const int*)d_in[0];     // [64][512] int32
  const float* emb  = (const float*)d_in[1];   // [32000][512] fp32
  const float* Wih  = (const float*)d_in[2];   // [512][4096] fp32
  const float* Whh  = (const float*)d_in[3];   // [1024][4096] fp32
  const float* bias = (const float*)d_in[4];   // [4096] fp32
  float* out = (float*)d_out;                  // h[64][1024] then c[64][1024]

  unsigned short* Wf    = (unsigned short*)d_ws;            // 12.6 MB
  unsigned short* Abufs = Wf + (size_t)NBLK * KC * 256 * 8; // 512*192KB = 100.7MB
  int* bar = (int*)(Abufs + (size_t)Ssz * AUNITS * 8);      // 1056 ints

  wf_kernel<<<dim3(G4 / 32, Ksz / 32), 1024, 0, stream>>>(Wih, Whh, Wf);
  init_kernel<<<Bsz, 256, 0, stream>>>(seq, emb, Abufs, bar);
  lstm_kernel<<<NBLK, 256, 0, stream>>>(seq, emb, bias, Wf, Abufs, bar, out);
}

// Round 6
// 3536.998 us; speedup vs baseline: 4.5653x; 2.3509x over previous
//
#include <hip/hip_runtime.h>
#include <stdint.h>

// LSTM encoder: B=64, S=512, V=32000, E=512, H=1024. Returns final (h, c) fp32.
//
// Round-6: 256 blocks (all CUs), COLS=4 h-cols/block -> W slice 48KB lives in
// LDS permanently (kills 12.6MB/step L2 W re-read; r5 had 64 CUs pulling
// 384KB/step each). A=[h|emb] still broadcast via virgin-buffer rotation
// (r5-validated): producers store h with sc1 (write-through to MALL),
// consumers use normal cached loads on never-touched lines -> XCD L2
// broadcasts to its 32 blocks. emb projections for ALL steps precomputed by
// init (no barrier dependence) -> the emb third of the K-loop (kc 32..47) is
// computed DURING the barrier wait. Gates land per-lane in MFMA C-layout
// (n-tile = gate), elementwise via small LDS exchange. h-stores + flags by
// wave 0 only. 2-level flag barrier (4 aggregators). Capacity sized for
// 2 blocks/CU (LDS 54KB, launch_bounds(256,2)) so all 256 resident under any
// packing.

#define Bsz 64
#define Ssz 512
#define Esz 512
#define Hsz 1024
#define G4  4096
#define Ksz 1536
#define KC  48      // Ksz/32
#define NBLK 256
#define AUNITS 12288            // 16B units per A buffer (KC*256)

typedef float f32x4 __attribute__((ext_vector_type(4)));
typedef short bf16x8 __attribute__((ext_vector_type(8)));
typedef unsigned long long u64;

// A unit(row,kc,q) = kc*256 + (row>>4)*64 + q*16 + (row&15)
//   -> wave w, lane l: frag(kc) = unit kc*256 + w*64 + l (coalesced 1KB/wave)
// Wf unit(blk,kc,q,r) = (blk*48+kc)*64 + q*16 + r, r = n-col = gate*4+j,
//   covering global gate-col gate*1024 + blk*4 + j.

__device__ __forceinline__ unsigned short f2bf(float f) {
  union { float f; uint32_t u; } v; v.f = f;
  return (unsigned short)((v.u + 0x7FFFu + ((v.u >> 16) & 1u)) >> 16);  // RNE
}
__device__ __forceinline__ float fsig(float x) {
  return __builtin_amdgcn_rcpf(1.0f + __expf(-x));
}
__device__ __forceinline__ float ftanh(float x) {
  return 2.0f * fsig(2.0f * x) - 1.0f;
}

// Build Wf from fp32 W_ih/W_hh with a 32x32 LDS transpose.
__global__ __launch_bounds__(1024) void wf_kernel(
    const float* __restrict__ Wih, const float* __restrict__ Whh,
    unsigned short* __restrict__ Wf)
{
  __shared__ float tile[32][33];
  const int j0 = blockIdx.x * 32;           // gate-col tile
  const int k0 = blockIdx.y * 32;           // k tile
  const int tx = threadIdx.x & 31, ty = threadIdx.x >> 5;
  const int k = k0 + ty;
  tile[ty][tx] = (k < Hsz) ? Whh[(size_t)k * G4 + (j0 + tx)]
                           : Wih[(size_t)(k - Hsz) * G4 + (j0 + tx)];
  __syncthreads();
  if (threadIdx.x < 128) {
    const int gl = threadIdx.x & 31;        // local gate col in tile
    const int q8 = threadIdx.x >> 5;        // k-octet within kc
    const int g  = j0 + gl;                 // global gate col
    const int blk  = (g & 1023) >> 2;
    const int gate = g >> 10;
    const int r    = gate * 4 + (g & 3);    // n-col within block tile
    const int kc   = k0 >> 5;
    unsigned short pack[8];
    #pragma unroll
    for (int jj = 0; jj < 8; ++jj) pack[jj] = f2bf(tile[q8 * 8 + jj][gl]);
    const size_t unit = (size_t)((blk * KC + kc) * 64 + q8 * 16 + r);
    *(bf16x8*)(Wf + unit * 8) = *(bf16x8*)pack;
  }
}

// Precompute emb region of EVERY A[t] (no recurrence dependence); zero A[0]'s
// h region; zero flags. grid = Ssz blocks x 256 threads; block t owns A[t].
__global__ __launch_bounds__(256) void init_kernel(
    const int* __restrict__ seq, const float* __restrict__ emb,
    unsigned short* __restrict__ Abufs, int* __restrict__ bar)
{
  const int t = blockIdx.x, tid = threadIdx.x;
  unsigned short* At = Abufs + (size_t)t * AUNITS * 8;
  const int c = 2 * tid;                    // emb col pair
  const int kc = 32 + (c >> 5), q = (c >> 3) & 3, j = c & 7;
  for (int row = 0; row < Bsz; ++row) {
    const int token = seq[row * Ssz + t];
    float2 e = ((const float2*)(emb + (size_t)token * Esz))[tid];
    uint32_t pe = (uint32_t)f2bf(e.x) | ((uint32_t)f2bf(e.y) << 16);
    const size_t unit = (size_t)(kc * 256 + (row >> 4) * 64 + q * 16 + (row & 15));
    *(uint32_t*)(At + unit * 8 + j) = pe;
  }
  if (t == 0) {
    // zero h region of A[0]: units 0..8191 (128KB)
    uint4 z; z.x = z.y = z.z = z.w = 0u;
    for (int i = tid; i < 8192; i += 256) ((uint4*)At)[i] = z;
    for (int i = tid; i < 4160; i += 256) bar[i] = 0;
  }
}

__global__ __launch_bounds__(256, 2) void lstm_kernel(
    const float* __restrict__ bias, const unsigned short* __restrict__ Wf,
    unsigned short* __restrict__ Abufs,
    int* __restrict__ bar, float* __restrict__ out)
{
  const int blk  = blockIdx.x;          // owns h-cols [blk*4, blk*4+4)
  const int tid  = threadIdx.x;
  const int lane = tid & 63;
  const int w    = tid >> 6;            // wave = M-tile rows [w*16, w*16+16)
  const int l15  = lane & 15, quad = lane >> 4;

  __shared__ uint4 Wl[KC * 64];         // 48 KB  W slice, resident all steps
  __shared__ float Gs[64][17];          // 4.25 KB gate pre-activations
  __shared__ unsigned short Hs[64][4];  // 512 B  h exchange

  // one-time: W slice -> LDS (12 x uint4 per thread, coalesced)
  {
    const uint4* wfb = (const uint4*)Wf + (size_t)blk * (KC * 64);
    for (int i = tid; i < KC * 64; i += 256) Wl[i] = wfb[i];
  }

  // elementwise ownership: thread -> (row = tid&63, h-col j = tid>>6)
  const int erow = tid & 63;
  const int ej   = tid >> 6;
  float creg = 0.f;
  const float bi  = bias[          blk * 4 + ej];
  const float bf_ = bias[  Hsz   + blk * 4 + ej];
  const float bg  = bias[2*Hsz   + blk * 4 + ej];
  const float bo  = bias[3*Hsz   + blk * 4 + ej];

  // wave0 h-store address (col base c = blk*4; 8B per lane = row)
  const int hkc = blk >> 3, hq = (blk >> 1) & 3, hj0 = (blk & 1) * 4;
  const size_t hunit = (size_t)(hkc * 256 + (lane >> 4) * 64 + hq * 16 + (lane & 15));

  int* arr = bar;            // 256 flags, stride 16 ints (64B lines)
  int* mid = bar + 4096;     // 4 flags, stride 16 ints
  __syncthreads();

  // emb-part partial sum for t=0 (A[0] emb region written by init)
  f32x4 accE = {0.f, 0.f, 0.f, 0.f};
  {
    const uint4* A0 = (const uint4*)Abufs;
    #pragma unroll
    for (int kc = 32; kc < KC; ++kc) {
      uint4 a = A0[kc * 256 + w * 64 + lane];
      uint4 b = Wl[kc * 64 + lane];
      accE = __builtin_amdgcn_mfma_f32_16x16x32_bf16(
          __builtin_bit_cast(bf16x8, a), __builtin_bit_cast(bf16x8, b), accE, 0, 0, 0);
    }
  }

  for (int t = 0; t < Ssz; ++t) {
    const uint4* Ac = (const uint4*)(Abufs + (size_t)t * AUNITS * 8);

    // ---- h-part GEMM (kc 0..31), seeded with the prefetched emb part ----
    f32x4 acc = accE;
    #pragma unroll 8
    for (int kc = 0; kc < 32; ++kc) {
      uint4 a = Ac[kc * 256 + w * 64 + lane];
      uint4 b = Wl[kc * 64 + lane];
      acc = __builtin_amdgcn_mfma_f32_16x16x32_bf16(
          __builtin_bit_cast(bf16x8, a), __builtin_bit_cast(bf16x8, b), acc, 0, 0, 0);
    }
    {
      // C/D layout: col n = lane&15, row = quad*4 + reg (+ w*16)
      const int mr = w * 16 + quad * 4;
      #pragma unroll
      for (int r = 0; r < 4; ++r) Gs[mr + r][l15] = acc[r];
    }
    __syncthreads();

    // ---- elementwise LSTM cell: 1 (row, col) per thread ----
    {
      float gi = Gs[erow][     ej] + bi;    // n = gate*4 + j
      float gf = Gs[erow][ 4 + ej] + bf_;
      float gg = Gs[erow][ 8 + ej] + bg;
      float go = Gs[erow][12 + ej] + bo;
      float c  = fsig(gf) * creg + fsig(gi) * ftanh(gg);
      creg = c;
      float h  = fsig(go) * ftanh(c);
      if (t == Ssz - 1) {
        out[(size_t)erow * Hsz + blk * 4 + ej] = h;
        out[(size_t)(Bsz * Hsz) + (size_t)erow * Hsz + blk * 4 + ej] = c;
      } else {
        Hs[erow][ej] = f2bf(h);
      }
    }
    __syncthreads();

    if (t < Ssz - 1) {
      unsigned short* An = Abufs + (size_t)(t + 1) * AUNITS * 8;
      if (w == 0) {
        // h row `lane` (4 bf16 = 8B) -> A[t+1], write-through to MALL
        u64 hp = *(const u64*)&Hs[lane][0];
        __hip_atomic_store((u64*)(An + hunit * 8 + hj0), hp,
                           __ATOMIC_RELAXED, __HIP_MEMORY_SCOPE_AGENT);
        __builtin_amdgcn_s_waitcnt(0);         // wave0's stores at MALL
        if (lane == 0)
          __hip_atomic_store(&arr[blk * 16], t + 1,
                             __ATOMIC_RELAXED, __HIP_MEMORY_SCOPE_AGENT);
        if (blk < 4) {                          // aggregator: lane i -> block blk*64+i
          while (__hip_atomic_load(&arr[(blk * 64 + lane) * 16],
                                   __ATOMIC_RELAXED, __HIP_MEMORY_SCOPE_AGENT)
                 < t + 1) {
            __builtin_amdgcn_s_sleep(1);
          }
          if (lane == 0)
            __hip_atomic_store(&mid[blk * 16], t + 1,
                               __ATOMIC_RELAXED, __HIP_MEMORY_SCOPE_AGENT);
        }
        if (lane < 4) {                         // release: poll 4 mid flags
          while (__hip_atomic_load(&mid[lane * 16],
                                   __ATOMIC_RELAXED, __HIP_MEMORY_SCOPE_AGENT)
                 < t + 1) {
            __builtin_amdgcn_s_sleep(1);
          }
        }
      }
      // waves 1-3 overlap the poll with t+1's emb-part GEMM (init-written,
      // no barrier dependence); wave0 does it after the poll.
      accE.x = 0.f; accE.y = 0.f; accE.z = 0.f; accE.w = 0.f;
      const uint4* An4 = (const uint4*)An;
      #pragma unroll
      for (int kc = 32; kc < KC; ++kc) {
        uint4 a = An4[kc * 256 + w * 64 + lane];
        uint4 b = Wl[kc * 64 + lane];
        accE = __builtin_amdgcn_mfma_f32_16x16x32_bf16(
            __builtin_bit_cast(bf16x8, a), __builtin_bit_cast(bf16x8, b), accE, 0, 0, 0);
      }
      __syncthreads();                          // release barrier block-wide
    }
  }
}

extern "C" void kernel_launch(void* const* d_in, const int* in_sizes, int n_in,
                              void* d_out, int out_size, void* d_ws, size_t ws_size,
                              hipStream_t stream) {
  (void)in_sizes; (void)n_in; (void)out_size; (void)ws_size;
  const int*   seq  = (const int*)d_in[0];     // [64][512] int32
  const float* emb  = (const float*)d_in[1];   // [32000][512] fp32
  const float* Wih  = (const float*)d_in[2];   // [512][4096] fp32
  const float* Whh  = (const float*)d_in[3];   // [1024][4096] fp32
  const float* bias = (const float*)d_in[4];   // [4096] fp32
  float* out = (float*)d_out;                  // h[64][1024] then c[64][1024]

  unsigned short* Wf    = (unsigned short*)d_ws;              // 12.58 MB
  unsigned short* Abufs = Wf + (size_t)NBLK * KC * 64 * 8;    // 512*192KB
  int* bar = (int*)(Abufs + (size_t)Ssz * AUNITS * 8);        // 4160 ints

  wf_kernel<<<dim3(G4 / 32, Ksz / 32), 1024, 0, stream>>>(Wih, Whh, Wf);
  init_kernel<<<Ssz, 256, 0, stream>>>(seq, emb, Abufs, bar);
  lstm_kernel<<<NBLK, 256, 0, stream>>>(bias, Wf, Abufs, bar, out);
}

// Round 7
// 3276.423 us; speedup vs baseline: 4.9284x; 1.0795x over previous
//
#include <hip/hip_runtime.h>
#include <stdint.h>

// LSTM encoder: B=64, S=512, V=32000, E=512, H=1024. Returns final (h, c) fp32.
//
// Round-7 (r6 skeleton + critical-path surgery):
//  - In-wave LSTM cell: N=16/block means each wave's MFMA acc holds all 4
//    gates for its 16 rows -> cell via __shfl_xor(4/8/12), owner lanes
//    (l15<4) keep c in registers. Gs LDS + 2 syncthreads deleted.
//  - h exits via tiny per-wave LDS transpose (same-wave DS pipe is in-order,
//    no barrier), then each wave stores its own rows (sc1) + drains.
//  - Single-hop byte-flag barrier: flags[blk] byte in 4 cachelines; tid0
//    stores (t+1)&0xFF after one syncthreads; every wave busy-polls 64 u32
//    (lane i -> f32[i], __all(v==pat)). No aggregator hops. Wrap-safe
//    (max skew 1 step).
//  - emb-GEMM for t+1 issued after arrival flag, BEFORE the poll -> fully
//    overlapped with straggler arrivals for every wave (r6 had wave0's emb
//    GEMM after release, serialized by the block-wide barrier).
//  - Explicit double-buffered h-GEMM (groups of 8 uint4) to force MLP~8.

#define Bsz 64
#define Ssz 512
#define Esz 512
#define Hsz 1024
#define G4  4096
#define Ksz 1536
#define KC  48      // Ksz/32
#define NBLK 256
#define AUNITS 12288            // 16B units per A buffer (KC*256)

typedef float f32x4 __attribute__((ext_vector_type(4)));
typedef short bf16x8 __attribute__((ext_vector_type(8)));
typedef unsigned long long u64;

// A unit(row,kc,q) = kc*256 + (row>>4)*64 + q*16 + (row&15)
// Wf unit(blk,kc,q,r) = (blk*48+kc)*64 + q*16 + r, r = gate*4+j  (n-col)

__device__ __forceinline__ unsigned short f2bf(float f) {
  union { float f; uint32_t u; } v; v.f = f;
  return (unsigned short)((v.u + 0x7FFFu + ((v.u >> 16) & 1u)) >> 16);  // RNE
}
__device__ __forceinline__ float fsig(float x) {
  return __builtin_amdgcn_rcpf(1.0f + __expf(-x));
}
__device__ __forceinline__ float ftanh(float x) {
  return 2.0f * fsig(2.0f * x) - 1.0f;
}

// Build Wf from fp32 W_ih/W_hh with a 32x32 LDS transpose.
__global__ __launch_bounds__(1024) void wf_kernel(
    const float* __restrict__ Wih, const float* __restrict__ Whh,
    unsigned short* __restrict__ Wf)
{
  __shared__ float tile[32][33];
  const int j0 = blockIdx.x * 32;           // gate-col tile
  const int k0 = blockIdx.y * 32;           // k tile
  const int tx = threadIdx.x & 31, ty = threadIdx.x >> 5;
  const int k = k0 + ty;
  tile[ty][tx] = (k < Hsz) ? Whh[(size_t)k * G4 + (j0 + tx)]
                           : Wih[(size_t)(k - Hsz) * G4 + (j0 + tx)];
  __syncthreads();
  if (threadIdx.x < 128) {
    const int gl = threadIdx.x & 31;        // local gate col in tile
    const int q8 = threadIdx.x >> 5;        // k-octet within kc
    const int g  = j0 + gl;                 // global gate col
    const int blk  = (g & 1023) >> 2;
    const int gate = g >> 10;
    const int r    = gate * 4 + (g & 3);    // n-col within block tile
    const int kc   = k0 >> 5;
    unsigned short pack[8];
    #pragma unroll
    for (int jj = 0; jj < 8; ++jj) pack[jj] = f2bf(tile[q8 * 8 + jj][gl]);
    const size_t unit = (size_t)((blk * KC + kc) * 64 + q8 * 16 + r);
    *(bf16x8*)(Wf + unit * 8) = *(bf16x8*)pack;
  }
}

// Precompute emb region of EVERY A[t]; zero A[0]'s h region; zero flags.
__global__ __launch_bounds__(256) void init_kernel(
    const int* __restrict__ seq, const float* __restrict__ emb,
    unsigned short* __restrict__ Abufs, int* __restrict__ bar)
{
  const int t = blockIdx.x, tid = threadIdx.x;
  unsigned short* At = Abufs + (size_t)t * AUNITS * 8;
  const int c = 2 * tid;                    // emb col pair
  const int kc = 32 + (c >> 5), q = (c >> 3) & 3, j = c & 7;
  for (int row = 0; row < Bsz; ++row) {
    const int token = seq[row * Ssz + t];
    float2 e = ((const float2*)(emb + (size_t)token * Esz))[tid];
    uint32_t pe = (uint32_t)f2bf(e.x) | ((uint32_t)f2bf(e.y) << 16);
    const size_t unit = (size_t)(kc * 256 + (row >> 4) * 64 + q * 16 + (row & 15));
    *(uint32_t*)(At + unit * 8 + j) = pe;
  }
  if (t == 0) {
    uint4 z; z.x = z.y = z.z = z.w = 0u;
    for (int i = tid; i < 8192; i += 256) ((uint4*)At)[i] = z;  // h region A[0]
    if (tid < 64) bar[tid] = 0;                                  // 256 byte flags
  }
}

__global__ __launch_bounds__(256) void lstm_kernel(
    const float* __restrict__ bias, const unsigned short* __restrict__ Wf,
    unsigned short* __restrict__ Abufs,
    int* __restrict__ bar, float* __restrict__ out)
{
  const int blk  = blockIdx.x;          // owns h-cols [blk*4, blk*4+4)
  const int tid  = threadIdx.x;
  const int lane = tid & 63;
  const int w    = tid >> 6;            // wave = M-tile rows [w*16, w*16+16)
  const int l15  = lane & 15, quad = lane >> 4;

  __shared__ uint4 Wl[KC * 64];                 // 48 KB, resident all steps
  __shared__ unsigned short Hs[4][16][4];       // 512 B per-wave h transpose

  {  // one-time: W slice -> LDS
    const uint4* wfb = (const uint4*)Wf + (size_t)blk * (KC * 64);
    for (int i = tid; i < KC * 64; i += 256) Wl[i] = wfb[i];
  }

  // cell ownership: lanes l15<4 own (rows w*16+quad*4+r, col blk*4+l15)
  const bool owner = (l15 < 4);
  const int  bj = blk * 4 + (l15 & 3);
  const float bi  = bias[bj],        bf_ = bias[Hsz + bj];
  const float bg_ = bias[2*Hsz + bj], bo  = bias[3*Hsz + bj];
  float creg[4] = {0.f, 0.f, 0.f, 0.f};

  // h-store addressing: lane i<16 stores row w*16+i, cols blk*4..+4 (8B)
  const int hkc = blk >> 3, hq = (blk >> 1) & 3, hj0 = (blk & 1) * 4;

  unsigned char* flags = (unsigned char*)bar;
  __syncthreads();

  // emb partial sum for t=0
  f32x4 accE = {0.f, 0.f, 0.f, 0.f};
  {
    const uint4* A0 = (const uint4*)Abufs;
    #pragma unroll 8
    for (int kc = 32; kc < KC; ++kc) {
      uint4 a = A0[kc * 256 + w * 64 + lane];
      accE = __builtin_amdgcn_mfma_f32_16x16x32_bf16(
          __builtin_bit_cast(bf16x8, a),
          __builtin_bit_cast(bf16x8, Wl[kc * 64 + lane]), accE, 0, 0, 0);
    }
  }

  for (int t = 0; t < Ssz; ++t) {
    // ---- wait for all blocks' h_{t-1} stores (single-hop flag poll) ----
    if (t > 0) {
      const uint32_t pat = 0x01010101u * (uint32_t)(t & 0xFF);
      while (!__all(__hip_atomic_load((const int*)bar + lane, __ATOMIC_RELAXED,
                                      __HIP_MEMORY_SCOPE_AGENT) == (int)pat)) {
      }
    }

    // ---- h-part GEMM (kc 0..31), double-buffered groups of 8 ----
    const uint4* Ac = (const uint4*)(Abufs + (size_t)t * AUNITS * 8);
    f32x4 acc = accE;
    uint4 b0[8], b1[8];
    #pragma unroll
    for (int i = 0; i < 8; ++i) b0[i] = Ac[i * 256 + w * 64 + lane];
    #pragma unroll
    for (int g = 0; g < 4; ++g) {
      uint4* cur = (g & 1) ? b1 : b0;
      uint4* nxt = (g & 1) ? b0 : b1;
      if (g < 3) {
        #pragma unroll
        for (int i = 0; i < 8; ++i)
          nxt[i] = Ac[((g + 1) * 8 + i) * 256 + w * 64 + lane];
      }
      #pragma unroll
      for (int i = 0; i < 8; ++i) {
        acc = __builtin_amdgcn_mfma_f32_16x16x32_bf16(
            __builtin_bit_cast(bf16x8, cur[i]),
            __builtin_bit_cast(bf16x8, Wl[(g * 8 + i) * 64 + lane]),
            acc, 0, 0, 0);
      }
    }

    // ---- in-wave LSTM cell: acc[r] = gate (l15>>2) of col (l15&3), row
    //      w*16+quad*4+r. Owners (l15<4) gather f/g/o via shfl_xor. ----
    float hv[4];
    #pragma unroll
    for (int r = 0; r < 4; ++r) {
      float gf = __shfl_xor(acc[r], 4);
      float gg = __shfl_xor(acc[r], 8);
      float go = __shfl_xor(acc[r], 12);
      float c  = fsig(gf + bf_) * creg[r]
               + fsig(acc[r] + bi) * ftanh(gg + bg_);
      float h  = fsig(go + bo) * ftanh(c);
      if (owner) { creg[r] = c; hv[r] = h; }
    }

    if (t == Ssz - 1) {
      if (owner) {
        #pragma unroll
        for (int r = 0; r < 4; ++r) {
          const int row = w * 16 + quad * 4 + r;
          out[(size_t)row * Hsz + bj] = hv[r];
          out[(size_t)(Bsz * Hsz) + (size_t)row * Hsz + bj] = creg[r];
        }
      }
      break;
    }

    // ---- per-wave transpose (col-major owners -> row-major 8B lanes) ----
    if (owner) {
      #pragma unroll
      for (int r = 0; r < 4; ++r) Hs[w][quad * 4 + r][l15] = f2bf(hv[r]);
    }
    // same-wave DS pipe is in-order; compiler inserts lgkmcnt before use
    unsigned short* An = Abufs + (size_t)(t + 1) * AUNITS * 8;
    if (lane < 16) {
      u64 hp = *(const u64*)&Hs[w][lane][0];
      const size_t unit = (size_t)(hkc * 256 + w * 64 + hq * 16 + lane);
      __hip_atomic_store((u64*)(An + unit * 8 + hj0), hp,
                         __ATOMIC_RELAXED, __HIP_MEMORY_SCOPE_AGENT);
    }
    __builtin_amdgcn_s_waitcnt(0);     // this wave's h-stores acked at MALL
    __syncthreads();                   // all 4 waves drained
    if (tid == 0) {
      __hip_atomic_store(flags + blk, (unsigned char)((t + 1) & 0xFF),
                         __ATOMIC_RELAXED, __HIP_MEMORY_SCOPE_AGENT);
    }

    // ---- emb-part GEMM for t+1 (virgin init-written lines; overlaps the
    //      other blocks' arrivals — poll happens at loop top) ----
    accE.x = 0.f; accE.y = 0.f; accE.z = 0.f; accE.w = 0.f;
    const uint4* An4 = (const uint4*)An;
    #pragma unroll 8
    for (int kc = 32; kc < KC; ++kc) {
      uint4 a = An4[kc * 256 + w * 64 + lane];
      accE = __builtin_amdgcn_mfma_f32_16x16x32_bf16(
          __builtin_bit_cast(bf16x8, a),
          __builtin_bit_cast(bf16x8, Wl[kc * 64 + lane]), accE, 0, 0, 0);
    }
  }
}

extern "C" void kernel_launch(void* const* d_in, const int* in_sizes, int n_in,
                              void* d_out, int out_size, void* d_ws, size_t ws_size,
                              hipStream_t stream) {
  (void)in_sizes; (void)n_in; (void)out_size; (void)ws_size;
  const int*   seq  = (const int*)d_in[0];     // [64][512] int32
  const float* emb  = (const float*)d_in[1];   // [32000][512] fp32
  const float* Wih  = (const float*)d_in[2];   // [512][4096] fp32
  const float* Whh  = (const float*)d_in[3];   // [1024][4096] fp32
  const float* bias = (const float*)d_in[4];   // [4096] fp32
  float* out = (float*)d_out;                  // h[64][1024] then c[64][1024]

  unsigned short* Wf    = (unsigned short*)d_ws;              // 12.58 MB
  unsigned short* Abufs = Wf + (size_t)NBLK * KC * 64 * 8;    // 512*192KB
  int* bar = (int*)(Abufs + (size_t)Ssz * AUNITS * 8);        // 64 ints (flags)

  wf_kernel<<<dim3(G4 / 32, Ksz / 32), 1024, 0, stream>>>(Wih, Whh, Wf);
  init_kernel<<<Ssz, 256, 0, stream>>>(seq, emb, Abufs, bar);
  lstm_kernel<<<NBLK, 256, 0, stream>>>(bias, Wf, Abufs, bar, out);
}